// Round 6
// baseline (2591.627 us; speedup 1.0000x reference)
//
#include <hip/hip_runtime.h>

#define Bn  16
#define Ln  256
#define D0n 64
#define Hn  128
#define H4n 512
#define Kn  512
#define BLn 4096   // Bn*Ln

typedef float f4 __attribute__((ext_vector_type(4)));

__device__ __forceinline__ float sigf(float x) { return 1.0f / (1.0f + expf(-x)); }

__device__ __forceinline__ float fma4v(f4 w, f4 x, float acc) {
    acc = fmaf(w.x, x.x, acc);
    acc = fmaf(w.y, x.y, acc);
    acc = fmaf(w.z, x.z, acc);
    acc = fmaf(w.w, x.w, acc);
    return acc;
}

__device__ __forceinline__ float dotn(const f4* __restrict__ a,
                                      const f4* __restrict__ w, int n4) {
    float a0 = 0.f, a1 = 0.f, a2 = 0.f, a3 = 0.f;
    for (int i = 0; i < n4; i += 4) {
        a0 = fma4v(a[i], w[i], a0);
        a1 = fma4v(a[i + 1], w[i + 1], a1);
        a2 = fma4v(a[i + 2], w[i + 2], a2);
        a3 = fma4v(a[i + 3], w[i + 3], a3);
    }
    return (a0 + a1) + (a2 + a3);
}

// ---- tiled GEMM: Y[r][c] = scale*(X[r].W[c]) + b[c]; tiles 64r x 64c -------
// grid (out_dim/64, rows/64), block 256. W tile staged in LDS (padded), X
// rows broadcast-loaded (same addr across wave -> L1). K in {64,128,256}.
__global__ __launch_bounds__(256)
void k_gemm(const float* __restrict__ X, const float* __restrict__ W,
            const float* __restrict__ b, float* __restrict__ Y,
            int K, int out_dim, int do_relu, float scale) {
    __shared__ f4 wt[4160];               // 64 x (K/4+1) max = 64x65
    const int K4 = K >> 2;
    const int st = K4 + 1;
    const int lg = __ffs(K4) - 1;
    const int tid = threadIdx.x;
    const int c = tid & 63, rpart = tid >> 6;
    const f4* W4 = (const f4*)W;
    const int per = (64 * K4) >> 8;       // K/16
    for (int i = 0; i < per; ++i) {
        int idx = i * 256 + tid;
        int row = idx >> lg, col = idx & (K4 - 1);
        wt[row * st + col] = W4[(size_t)(blockIdx.x * 64 + row) * K4 + col];
    }
    __syncthreads();
    const f4* X4 = (const f4*)X;
    const float bc = b ? b[blockIdx.x * 64 + c] : 0.f;
    const f4* wrow = wt + c * st;
    for (int i = 0; i < 16; ++i) {
        int r = blockIdx.y * 64 + i * 4 + rpart;
        const f4* xr = X4 + (size_t)r * K4;
        float a0 = 0.f, a1 = 0.f, a2 = 0.f, a3 = 0.f;
        for (int k = 0; k < K4; k += 4) {
            a0 = fma4v(wrow[k],     xr[k],     a0);
            a1 = fma4v(wrow[k + 1], xr[k + 1], a1);
            a2 = fma4v(wrow[k + 2], xr[k + 2], a2);
            a3 = fma4v(wrow[k + 3], xr[k + 3], a3);
        }
        float acc = scale * ((a0 + a1) + (a2 + a3)) + bc;
        if (do_relu) acc = fmaxf(acc, 0.f);
        Y[(size_t)r * out_dim + blockIdx.x * 64 + c] = acc;
    }
}

// -------- small transpose: out[c][r] = in[r][c] --------
__global__ void k_transpose(const float* __restrict__ in, float* __restrict__ out,
                            int R, int C) {
    int idx = blockIdx.x * blockDim.x + threadIdx.x;
    if (idx >= R * C) return;
    int c = idx / R, r = idx % R;
    out[idx] = in[(size_t)r * C + c];
}

// ---- rearrange gate weights [512][32]f4 -> f4-major with quadrant split ----
// side s, thread tid(0..255): q=tid>>6, j=tid&63 -> global row q*128+s*64+j.
// out[f*512 + s*256 + tid] = in[row*32 + f]
__global__ void k_rearrG2(const f4* __restrict__ in, f4* __restrict__ out) {
    int idx = blockIdx.x * blockDim.x + threadIdx.x;   // 16384
    if (idx >= 16384) return;
    int f = idx >> 9, r = idx & 511, s = r >> 8, t = r & 255;
    int row = (t >> 6) * 128 + s * 64 + (t & 63);
    out[idx] = in[(size_t)row * 32 + f];
}

// ---- rearrange W1 [128][16]f4 -> out[f*256+tid], row=tid>>1, half=tid&1 ----
__global__ void k_rearrW12(const f4* __restrict__ in, f4* __restrict__ out) {
    int idx = blockIdx.x * blockDim.x + threadIdx.x;   // 2048
    if (idx >= 2048) return;
    int f = idx >> 8, t = idx & 255;
    out[idx] = in[((size_t)(t >> 1)) * 16 + (t & 1) * 8 + f];
}

__global__ void k_zero(int* __restrict__ p, int n) {
    int i = blockIdx.x * blockDim.x + threadIdx.x;
    if (i < n) p[i] = 0;
}

// -------- cst[p] = scale*(bq . kp[p]) + (mask[p]==0 ? -1e9 : 0) --------
__global__ void k_cst(const float* __restrict__ kp, const float* __restrict__ bq,
                      const float* __restrict__ mask, float* __restrict__ cst) {
    int p = blockIdx.x * blockDim.x + threadIdx.x;
    if (p >= BLn) return;
    float a = dotn((const f4*)bq, (const f4*)(kp + (size_t)p * Hn), Hn >> 2);
    cst[p] = a * 0.088388347648318447f + (mask[p] == 0.f ? -1e9f : 0.f);
}

// -------- LSTM scan: 1024 thr, 2 thr/row, pinned half-row; writes hcat ------
__global__ __launch_bounds__(1024)
void k_lstm_scan(const float* __restrict__ xWf, const float* __restrict__ xWb,
                 const float* __restrict__ Whh_f, const float* __restrict__ Whh_b,
                 float* __restrict__ hcat) {
    const int b   = blockIdx.x & 15;
    const int rev = blockIdx.x >> 4;
    const int tid = threadIdx.x;
    const int row  = tid >> 1;
    const int half = tid & 1;
    const float* xW  = rev ? xWb : xWf;
    const float* Whh = rev ? Whh_b : Whh_f;
    float*       ho  = hcat + rev * Hn;      // fwd -> [0:128), bwd -> [128:256)

    __shared__ __align__(16) float h_s[Hn];
    __shared__ __align__(16) float g_s[H4n];

    float c_reg = 0.f;
    if (tid < Hn) h_s[tid] = 0.f;

    f4 w[16];
    {
        const f4* p = (const f4*)(Whh + (size_t)row * Hn + half * 64);
#pragma unroll
        for (int i = 0; i < 16; ++i) w[i] = p[i];
#pragma unroll
        for (int i = 0; i < 16; ++i) asm volatile("" : "+v"(w[i]));
    }
    const int t0 = rev ? (Ln - 1) : 0;
    float xw_v = (half == 0) ? xW[((size_t)b * Ln + t0) * H4n + row] : 0.f;
    __syncthreads();

    for (int s = 0; s < Ln; ++s) {
        const int t = rev ? (Ln - 1 - s) : s;
        float xw_n = 0.f;
        if (half == 0 && s + 1 < Ln) {
            int tn = rev ? (Ln - 2 - s) : (s + 1);
            xw_n = xW[((size_t)b * Ln + tn) * H4n + row];
        }
        const f4* hh = (const f4*)(h_s + half * 64);
        float a0 = 0.f, a1 = 0.f, a2 = 0.f, a3 = 0.f;
#pragma unroll
        for (int i = 0; i < 16; i += 4) {
            a0 = fma4v(w[i], hh[i], a0);
            a1 = fma4v(w[i + 1], hh[i + 1], a1);
            a2 = fma4v(w[i + 2], hh[i + 2], a2);
            a3 = fma4v(w[i + 3], hh[i + 3], a3);
        }
        float acc = (a0 + a1) + (a2 + a3);
        acc += __shfl_xor(acc, 1);
        if (half == 0) g_s[row] = acc + xw_v;
        __syncthreads();
        if (tid < Hn) {
            float ig = sigf(g_s[tid]);
            float fg = sigf(g_s[Hn + tid]);
            float gg = tanhf(g_s[2 * Hn + tid]);
            float og = sigf(g_s[3 * Hn + tid]);
            c_reg = fg * c_reg + ig * gg;
            float hv = og * tanhf(c_reg);
            h_s[tid] = hv;
            ho[((size_t)b * Ln + t) * (2 * Hn) + tid] = hv;
        }
        __syncthreads();
        xw_v = xw_n;
    }
}

// -------- codebook squared norms --------
__global__ void k_codenorm(const float* __restrict__ emb, float* __restrict__ c2) {
    int k = blockIdx.x * blockDim.x + threadIdx.x;
    if (k >= Kn) return;
    const f4* e4 = (const f4*)(emb + (size_t)k * Hn);
    float acc = 0.f;
    for (int i = 0; i < Hn / 4; ++i) {
        f4 v = e4[i];
        acc = fmaf(v.x, v.x, acc); acc = fmaf(v.y, v.y, acc);
        acc = fmaf(v.z, v.z, acc); acc = fmaf(v.w, v.w, acc);
    }
    c2[k] = acc;
}

// -------- VQ pick: argmin over dist row (first-index ties) + gather ---------
__global__ __launch_bounds__(128)
void k_vqpick(const float* __restrict__ dist, const float* __restrict__ emb,
              float* __restrict__ zq) {
    const int p = blockIdx.x, tid = threadIdx.x;
    __shared__ int best_s;
    if (tid < 64) {
        float best = 3.0e38f; int bi = 0;
        for (int j = 0; j < 8; ++j) {
            int k = j * 64 + tid;
            float d = dist[(size_t)p * Kn + k];
            if (d < best) { best = d; bi = k; }
        }
        for (int off = 32; off > 0; off >>= 1) {
            float ov = __shfl_xor(best, off);
            int   oi = __shfl_xor(bi, off);
            if (ov < best || (ov == best && oi < bi)) { best = ov; bi = oi; }
        }
        if (tid == 0) best_s = bi;
    }
    __syncthreads();
    zq[(size_t)p * Hn + tid] = emb[(size_t)best_s * Hn + tid];
}

// -------- decoder: 2 blocks/batch x 256 thr, full register residency --------
// side s owns gate rows {q*128 + s*64 + j : q=0..3, j=0..63} -> computes
// c,h for components s*64+j locally; exchanges only 64 h floats per step.
// Pinned: whh 32f4 + wih 32f4 + w1r 8f4 + vwr 64f = 353 VGPR.
__global__ __launch_bounds__(256, 1)
void k_decoder(const float* __restrict__ kq_g, const float* __restrict__ vw_g,
               const float* __restrict__ cst_g,
               const float* __restrict__ W1R,  const float* __restrict__ b1_g,
               const float* __restrict__ WihR, const float* __restrict__ WhhR,
               const float* __restrict__ bd_g,
               float* gx, int* flags,
               float* __restrict__ dec_out, float* __restrict__ attn_w) {
    const int b    = blockIdx.x & 15;
    const int side = blockIdx.x >> 4;     // b and b+16 map to the same XCD (%8)
    const int tid  = threadIdx.x;

    __shared__ __align__(16) f4 kq_lds[Ln * 32];       // 128 KB swizzled
    __shared__ __align__(16) float tok_s[D0n];
    __shared__ __align__(16) float x_s[Hn];
    __shared__ __align__(16) float h_s[Hn];
    __shared__ __align__(16) float g_s[256];
    __shared__ float s_s[Ln];
    __shared__ float attn_sp[4][65];
    __shared__ float cst_s[Ln];
    __shared__ __align__(16) float b1_s[Hn];

    // ---- pinned weights ----
    const f4* WhhR4 = (const f4*)WhhR;
    const f4* WihR4 = (const f4*)WihR;
    const f4* W1R4  = (const f4*)W1R;
    f4 whh[32], wih[32], w1r[8];
#pragma unroll
    for (int f = 0; f < 32; ++f) whh[f] = WhhR4[f * 512 + side * 256 + tid];
#pragma unroll
    for (int f = 0; f < 32; ++f) wih[f] = WihR4[f * 512 + side * 256 + tid];
#pragma unroll
    for (int f = 0; f < 8; ++f)  w1r[f] = W1R4[f * 256 + tid];
    const int grow = (tid >> 6) * 128 + side * 64 + (tid & 63);
    float bdr = bd_g[grow];
    const int o = tid >> 2, opart = tid & 3;           // out phase map
    float vwr[64];
#pragma unroll
    for (int l = 0; l < 64; ++l)
        vwr[l] = vw_g[((size_t)b * Ln + opart * 64 + l) * D0n + o];
#pragma unroll
    for (int f = 0; f < 32; ++f) asm volatile("" : "+v"(whh[f]));
#pragma unroll
    for (int f = 0; f < 32; ++f) asm volatile("" : "+v"(wih[f]));
#pragma unroll
    for (int f = 0; f < 8; ++f)  asm volatile("" : "+v"(w1r[f]));
#pragma unroll
    for (int l = 0; l < 64; ++l) asm volatile("" : "+v"(vwr[l]));
    asm volatile("" : "+v"(bdr));

    // ---- stage KQ into LDS with XOR swizzle (phys f4 = f ^ (l&7)) ----
    const f4* kq4 = (const f4*)(kq_g + (size_t)b * Ln * Hn);
#pragma unroll
    for (int it = 0; it < 32; ++it) {
        int idx = it * 256 + tid;
        int l = idx >> 5, f = idx & 31;
        kq_lds[l * 32 + (f ^ (l & 7))] = kq4[idx];
    }
    if (tid < D0n) tok_s[tid] = 0.f;
    if (tid < Hn)  { h_s[tid] = 0.f; b1_s[tid] = b1_g[tid]; }
    cst_s[tid] = cst_g[(size_t)b * Ln + tid];
    float c_reg = 0.f;
    __syncthreads();

    float* gx_mine = gx + (b * 2 + side) * 128;
    float* gx_peer = gx + (b * 2 + (side ^ 1)) * 128;
    int* flag_mine = flags + (b * 2 + side);
    int* flag_peer = flags + (b * 2 + (side ^ 1));

    const int arow = tid >> 1, apart = tid & 1;        // x phase map

    for (int t = 0; t < Ln; ++t) {
        // ---- A: x = relu(W1 @ tok + b1); 128 rows x 2 halves ----
        {
            const f4* t4 = (const f4*)tok_s;
            float u0 = 0.f, u1 = 0.f;
#pragma unroll
            for (int f = 0; f < 8; f += 2) {
                u0 = fma4v(w1r[f],     t4[apart * 8 + f],     u0);
                u1 = fma4v(w1r[f + 1], t4[apart * 8 + f + 1], u1);
            }
            float a = u0 + u1;
            a += __shfl_xor(a, 1);
            if (apart == 0) x_s[arow] = fmaxf(a + b1_s[arow], 0.f);
        }
        __syncthreads();
        // ---- gates: own row per thread, all weights in VGPRs ----
        {
            const f4* x4 = (const f4*)x_s;
            const f4* h4 = (const f4*)h_s;
            float a0 = 0.f, a1 = 0.f, a2 = 0.f, a3 = 0.f;
#pragma unroll
            for (int f = 0; f < 32; f += 4) {
                a0 = fma4v(wih[f],     x4[f],     a0);
                a1 = fma4v(wih[f + 1], x4[f + 1], a1);
                a2 = fma4v(wih[f + 2], x4[f + 2], a2);
                a3 = fma4v(wih[f + 3], x4[f + 3], a3);
            }
#pragma unroll
            for (int f = 0; f < 32; f += 4) {
                a0 = fma4v(whh[f],     h4[f],     a0);
                a1 = fma4v(whh[f + 1], h4[f + 1], a1);
                a2 = fma4v(whh[f + 2], h4[f + 2], a2);
                a3 = fma4v(whh[f + 3], h4[f + 3], a3);
            }
            g_s[tid] = (a0 + a1) + (a2 + a3) + bdr;
        }
        __syncthreads();
        // ---- cell for own 64 components; h -> LDS + peer buffer ----
        if (tid < 64) {
            float ig = sigf(g_s[tid]);
            float fg = sigf(g_s[64 + tid]);
            float gg = tanhf(g_s[128 + tid]);
            float og = sigf(g_s[192 + tid]);
            c_reg = fg * c_reg + ig * gg;
            float hv = og * tanhf(c_reg);
            h_s[side * 64 + tid] = hv;
            __hip_atomic_store(&gx_mine[(t & 1) * 64 + tid], hv,
                               __ATOMIC_RELAXED, __HIP_MEMORY_SCOPE_AGENT);
        }
        __syncthreads();   // drains vmcnt: h stores complete
        if (tid == 0) {
            __hip_atomic_store(flag_mine, t + 1, __ATOMIC_RELEASE, __HIP_MEMORY_SCOPE_AGENT);
            while (__hip_atomic_load(flag_peer, __ATOMIC_ACQUIRE, __HIP_MEMORY_SCOPE_AGENT) < t + 1) {}
        }
        __syncthreads();
        if (tid < 64)
            h_s[(side ^ 1) * 64 + tid] =
                __hip_atomic_load(&gx_peer[(t & 1) * 64 + tid],
                                  __ATOMIC_RELAXED, __HIP_MEMORY_SCOPE_AGENT);
        __syncthreads();
        // ---- scores: s[l] = h . KQ[l] + cst[l]; one l per thread ----
        {
            const f4* h4 = (const f4*)h_s;
            const int l = tid;
            float e0 = 0.f, e1 = 0.f, e2 = 0.f, e3 = 0.f;
#pragma unroll
            for (int f = 0; f < 32; f += 4) {
                e0 = fma4v(kq_lds[l * 32 + ((f)     ^ (l & 7))], h4[f],     e0);
                e1 = fma4v(kq_lds[l * 32 + ((f + 1) ^ (l & 7))], h4[f + 1], e1);
                e2 = fma4v(kq_lds[l * 32 + ((f + 2) ^ (l & 7))], h4[f + 2], e2);
                e3 = fma4v(kq_lds[l * 32 + ((f + 3) ^ (l & 7))], h4[f + 3], e3);
            }
            s_s[l] = (e0 + e1) + (e2 + e3) + cst_s[l];
        }
        __syncthreads();
        // ---- softmax, wave 0 only; side 0 writes attn_w ----
        if (tid < 64) {
            float v0 = s_s[tid],       v1 = s_s[tid + 64];
            float v2 = s_s[tid + 128], v3 = s_s[tid + 192];
            float m = fmaxf(fmaxf(v0, v1), fmaxf(v2, v3));
#pragma unroll
            for (int o2 = 32; o2 > 0; o2 >>= 1) m = fmaxf(m, __shfl_xor(m, o2));
            float e0 = expf(v0 - m), e1 = expf(v1 - m);
            float e2 = expf(v2 - m), e3 = expf(v3 - m);
            float s = (e0 + e1) + (e2 + e3);
#pragma unroll
            for (int o2 = 32; o2 > 0; o2 >>= 1) s += __shfl_xor(s, o2);
            float inv = 1.f / s;
            e0 *= inv; e1 *= inv; e2 *= inv; e3 *= inv;
            attn_sp[0][tid] = e0; attn_sp[1][tid] = e1;
            attn_sp[2][tid] = e2; attn_sp[3][tid] = e3;
            if (side == 0) {
                float* aw = attn_w + ((size_t)b * Ln + t) * Ln;
                aw[tid] = e0; aw[tid + 64] = e1;
                aw[tid + 128] = e2; aw[tid + 192] = e3;
            }
        }
        __syncthreads();
        // ---- out[o] = sum_l attn[l]*VW'[l][o]; 64 o x 4 parts ----
        {
            const float* as = attn_sp[opart];
            float g0 = 0.f, g1 = 0.f, g2 = 0.f, g3 = 0.f;
#pragma unroll
            for (int l = 0; l < 64; l += 4) {
                g0 = fmaf(as[l],     vwr[l],     g0);
                g1 = fmaf(as[l + 1], vwr[l + 1], g1);
                g2 = fmaf(as[l + 2], vwr[l + 2], g2);
                g3 = fmaf(as[l + 3], vwr[l + 3], g3);
            }
            float a = (g0 + g1) + (g2 + g3);
            a += __shfl_xor(a, 1);
            a += __shfl_xor(a, 2);
            if (opart == 0) {
                tok_s[o] = a;
                if (side == 1) dec_out[((size_t)b * Ln + t) * D0n + o] = a;
            }
        }
        __syncthreads();
    }
}

extern "C" void kernel_launch(void* const* d_in, const int* in_sizes, int n_in,
                              void* d_out, int out_size, void* d_ws, size_t ws_size,
                              hipStream_t stream) {
    const float* inputs     = (const float*)d_in[0];
    const float* in_mask    = (const float*)d_in[2];
    const float* enc_lin1_W = (const float*)d_in[3];
    const float* enc_lin1_b = (const float*)d_in[4];
    const float* enc_Wih_f  = (const float*)d_in[5];
    const float* enc_Whh_f  = (const float*)d_in[6];
    const float* enc_b_f    = (const float*)d_in[7];
    const float* enc_Wih_b  = (const float*)d_in[8];
    const float* enc_Whh_b  = (const float*)d_in[9];
    const float* enc_b_b    = (const float*)d_in[10];
    const float* enc_lin2_W = (const float*)d_in[11];
    const float* enc_lin2_b = (const float*)d_in[12];
    const float* vq_emb     = (const float*)d_in[13];
    const float* dec_lin1_W = (const float*)d_in[14];
    const float* dec_lin1_b = (const float*)d_in[15];
    const float* dec_Wih    = (const float*)d_in[16];
    const float* dec_Whh    = (const float*)d_in[17];
    const float* dec_b      = (const float*)d_in[18];
    const float* attn_Wq    = (const float*)d_in[19];
    const float* attn_bq    = (const float*)d_in[20];
    const float* attn_Wk    = (const float*)d_in[21];
    const float* attn_bk    = (const float*)d_in[22];
    const float* attn_Wv    = (const float*)d_in[23];
    const float* attn_bv    = (const float*)d_in[24];
    const float* dec_lin2_W = (const float*)d_in[25];
    const float* dec_lin2_b = (const float*)d_in[26];

    float* out     = (float*)d_out;
    float* dec_out = out;                       // 16*256*64   = 262144
    float* attn_w  = out + 262144;              // 16*256*256  = 1048576
    float* ze      = out + 1310720;             // 16*256*128  = 524288
    float* zq      = out + 1835008;             // 16*256*128  = 524288

    float* ws    = (float*)d_ws;
    float* enc_x = ws;                          // 524288
    float* xWf   = enc_x + 524288;              // 2097152
    float* xWb   = xWf + 2097152;               // 2097152
    float* hcat  = xWb + 2097152;               // 1048576 (hf|hb interleaved rows)
    float* kp    = hcat + 1048576;              // 524288
    float* vp    = kp + 524288;                 // 524288
    float* c2    = vp + 524288;                 // 512
    float* gxbuf = c2 + 512;                    // 16*2*128 = 4096
    int*   flags = (int*)(gxbuf + 4096);        // 32 ints
    // aliases into dead regions:
    float* WqT   = enc_x;                       // enc_x dead after xWf/xWb
    float* WhhR  = enc_x + 16384;               // 65536
    float* WihR  = enc_x + 16384 + 65536;       // 65536
    float* W1R   = enc_x + 16384 + 2 * 65536;   // 8192
    float* dist  = xWf;                         // 4096*512 = 2097152 (dead post-LSTM)
    float* kq    = xWb;                         // 524288  (dead post-LSTM)
    float* vw    = xWb + 524288;                // 262144
    float* cst   = xWb + 786432;                // 4096

    dim3 blk(256);
    // ---- encoder front ----
    k_gemm<<<dim3(2, 64), blk, 0, stream>>>(inputs, enc_lin1_W, enc_lin1_b, enc_x, D0n, Hn, 1, 1.f);
    k_gemm<<<dim3(8, 64), blk, 0, stream>>>(enc_x, enc_Wih_f, enc_b_f, xWf, Hn, H4n, 0, 1.f);
    k_gemm<<<dim3(8, 64), blk, 0, stream>>>(enc_x, enc_Wih_b, enc_b_b, xWb, Hn, H4n, 0, 1.f);
    // ---- weight rearrangements into enc_x region (dead now) ----
    k_transpose<<<64, 256, 0, stream>>>(attn_Wq, WqT, Hn, Hn);
    k_rearrG2<<<64, 256, 0, stream>>>((const f4*)dec_Whh, (f4*)WhhR);
    k_rearrG2<<<64, 256, 0, stream>>>((const f4*)dec_Wih, (f4*)WihR);
    k_rearrW12<<<8, 256, 0, stream>>>((const f4*)dec_lin1_W, (f4*)W1R);
    k_zero<<<1, 64, 0, stream>>>(flags, 32);
    // ---- BiLSTM ----
    k_lstm_scan<<<32, 1024, 0, stream>>>(xWf, xWb, enc_Whh_f, enc_Whh_b, hcat);
    k_gemm<<<dim3(2, 64), blk, 0, stream>>>(hcat, enc_lin2_W, enc_lin2_b, ze, 2 * Hn, Hn, 0, 1.f);
    // ---- VQ: dist GEMM + argmin/gather ----
    k_codenorm<<<2, 256, 0, stream>>>(vq_emb, c2);
    k_gemm<<<dim3(8, 64), blk, 0, stream>>>(ze, vq_emb, c2, dist, Hn, Kn, 0, -2.f);
    k_vqpick<<<BLn, 128, 0, stream>>>(dist, vq_emb, zq);
    // ---- attention precomputes (dec_in == zq) ----
    k_gemm<<<dim3(2, 64), blk, 0, stream>>>(zq, attn_Wk, attn_bk, kp, Hn, Hn, 0, 1.f);
    k_gemm<<<dim3(2, 64), blk, 0, stream>>>(zq, attn_Wv, attn_bv, vp, Hn, Hn, 0, 1.f);
    k_gemm<<<dim3(2, 64), blk, 0, stream>>>(kp, WqT, nullptr, kq, Hn, Hn, 0, 0.088388347648318447f);
    k_gemm<<<dim3(1, 64), blk, 0, stream>>>(vp, dec_lin2_W, dec_lin2_b, vw, Hn, D0n, 0, 1.f);
    k_cst<<<Bn, 256, 0, stream>>>(kp, attn_bq, in_mask, cst);
    // ---- decoder: 32 blocks = 16 batches x 2 sides ----
    k_decoder<<<32, 256, 0, stream>>>(kq, vw, cst,
                                      W1R, dec_lin1_b,
                                      WihR, WhhR, dec_b,
                                      gxbuf, flags,
                                      dec_out, attn_w);
}

// Round 7
// 1871.345 us; speedup vs baseline: 1.3849x; 1.3849x over previous
//
#include <hip/hip_runtime.h>

#define Bn  16
#define Ln  256
#define D0n 64
#define Hn  128
#define H4n 512
#define Kn  512
#define BLn 4096   // Bn*Ln

typedef float f4 __attribute__((ext_vector_type(4)));

__device__ __forceinline__ float sigf(float x) { return 1.0f / (1.0f + expf(-x)); }

__device__ __forceinline__ float fma4v(f4 w, f4 x, float acc) {
    acc = fmaf(w.x, x.x, acc);
    acc = fmaf(w.y, x.y, acc);
    acc = fmaf(w.z, x.z, acc);
    acc = fmaf(w.w, x.w, acc);
    return acc;
}

__device__ __forceinline__ float dotn(const f4* __restrict__ a,
                                      const f4* __restrict__ w, int n4) {
    float a0 = 0.f, a1 = 0.f, a2 = 0.f, a3 = 0.f;
    for (int i = 0; i < n4; i += 4) {
        a0 = fma4v(a[i], w[i], a0);
        a1 = fma4v(a[i + 1], w[i + 1], a1);
        a2 = fma4v(a[i + 2], w[i + 2], a2);
        a3 = fma4v(a[i + 3], w[i + 3], a3);
    }
    return (a0 + a1) + (a2 + a3);
}

// ---- tiled GEMM: Y[r][c] = scale*(X[r].W[c]) + b[c]; tiles 64r x 64c -------
__global__ __launch_bounds__(256)
void k_gemm(const float* __restrict__ X, const float* __restrict__ W,
            const float* __restrict__ b, float* __restrict__ Y,
            int K, int out_dim, int do_relu, float scale) {
    __shared__ f4 wt[4160];               // 64 x (K/4+1) max = 64x65
    const int K4 = K >> 2;
    const int st = K4 + 1;
    const int lg = __ffs(K4) - 1;
    const int tid = threadIdx.x;
    const int c = tid & 63, rpart = tid >> 6;
    const f4* W4 = (const f4*)W;
    const int per = (64 * K4) >> 8;       // K/16
    for (int i = 0; i < per; ++i) {
        int idx = i * 256 + tid;
        int row = idx >> lg, col = idx & (K4 - 1);
        wt[row * st + col] = W4[(size_t)(blockIdx.x * 64 + row) * K4 + col];
    }
    __syncthreads();
    const f4* X4 = (const f4*)X;
    const float bc = b ? b[blockIdx.x * 64 + c] : 0.f;
    const f4* wrow = wt + c * st;
    for (int i = 0; i < 16; ++i) {
        int r = blockIdx.y * 64 + i * 4 + rpart;
        const f4* xr = X4 + (size_t)r * K4;
        float a0 = 0.f, a1 = 0.f, a2 = 0.f, a3 = 0.f;
        for (int k = 0; k < K4; k += 4) {
            a0 = fma4v(wrow[k],     xr[k],     a0);
            a1 = fma4v(wrow[k + 1], xr[k + 1], a1);
            a2 = fma4v(wrow[k + 2], xr[k + 2], a2);
            a3 = fma4v(wrow[k + 3], xr[k + 3], a3);
        }
        float acc = scale * ((a0 + a1) + (a2 + a3)) + bc;
        if (do_relu) acc = fmaxf(acc, 0.f);
        Y[(size_t)r * out_dim + blockIdx.x * 64 + c] = acc;
    }
}

// -------- small transpose: out[c][r] = in[r][c] --------
__global__ void k_transpose(const float* __restrict__ in, float* __restrict__ out,
                            int R, int C) {
    int idx = blockIdx.x * blockDim.x + threadIdx.x;
    if (idx >= R * C) return;
    int c = idx / R, r = idx % R;
    out[idx] = in[(size_t)r * C + c];
}

// ---- rearrange gate weights for quadrant-split, 512-thr, half-row layout ----
// side s, thread tid: q=tid>>7, jj=(tid>>1)&63, half=tid&1 -> row q*128+s*64+jj
// out[f*1024 + s*512 + tid] = in[row*32 + half*16 + f],  f in [0,16)
__global__ void k_rearrG3(const f4* __restrict__ in, f4* __restrict__ out) {
    int idx = blockIdx.x * blockDim.x + threadIdx.x;   // 16384
    if (idx >= 16384) return;
    int f = idx >> 10, rem = idx & 1023, s = rem >> 9, tid = rem & 511;
    int row = (tid >> 7) * 128 + s * 64 + ((tid >> 1) & 63);
    out[idx] = in[(size_t)row * 32 + (tid & 1) * 16 + f];
}

// ---- rearrange W1 [128][16]f4 -> out[f*512+tid], row=tid>>2, part=tid&3 ----
__global__ void k_rearrW14(const f4* __restrict__ in, f4* __restrict__ out) {
    int idx = blockIdx.x * blockDim.x + threadIdx.x;   // 2048
    if (idx >= 2048) return;
    int f = idx >> 9, t = idx & 511;
    out[idx] = in[((size_t)(t >> 2)) * 16 + (t & 3) * 4 + f];
}

__global__ void k_zero(int* __restrict__ p, int n) {
    int i = blockIdx.x * blockDim.x + threadIdx.x;
    if (i < n) p[i] = 0;
}

// -------- cst[p] = scale*(bq . kp[p]) + (mask[p]==0 ? -1e9 : 0) --------
__global__ void k_cst(const float* __restrict__ kp, const float* __restrict__ bq,
                      const float* __restrict__ mask, float* __restrict__ cst) {
    int p = blockIdx.x * blockDim.x + threadIdx.x;
    if (p >= BLn) return;
    float a = dotn((const f4*)bq, (const f4*)(kp + (size_t)p * Hn), Hn >> 2);
    cst[p] = a * 0.088388347648318447f + (mask[p] == 0.f ? -1e9f : 0.f);
}

// -------- LSTM scan: 1024 thr, 2 thr/row, pinned half-row; writes hcat ------
__global__ __launch_bounds__(1024)
void k_lstm_scan(const float* __restrict__ xWf, const float* __restrict__ xWb,
                 const float* __restrict__ Whh_f, const float* __restrict__ Whh_b,
                 float* __restrict__ hcat) {
    const int b   = blockIdx.x & 15;
    const int rev = blockIdx.x >> 4;
    const int tid = threadIdx.x;
    const int row  = tid >> 1;
    const int half = tid & 1;
    const float* xW  = rev ? xWb : xWf;
    const float* Whh = rev ? Whh_b : Whh_f;
    float*       ho  = hcat + rev * Hn;      // fwd -> [0:128), bwd -> [128:256)

    __shared__ __align__(16) float h_s[Hn];
    __shared__ __align__(16) float g_s[H4n];

    float c_reg = 0.f;
    if (tid < Hn) h_s[tid] = 0.f;

    f4 w[16];
    {
        const f4* p = (const f4*)(Whh + (size_t)row * Hn + half * 64);
#pragma unroll
        for (int i = 0; i < 16; ++i) w[i] = p[i];
#pragma unroll
        for (int i = 0; i < 16; ++i) asm volatile("" : "+v"(w[i]));
    }
    const int t0 = rev ? (Ln - 1) : 0;
    float xw_v = (half == 0) ? xW[((size_t)b * Ln + t0) * H4n + row] : 0.f;
    __syncthreads();

    for (int s = 0; s < Ln; ++s) {
        const int t = rev ? (Ln - 1 - s) : s;
        float xw_n = 0.f;
        if (half == 0 && s + 1 < Ln) {
            int tn = rev ? (Ln - 2 - s) : (s + 1);
            xw_n = xW[((size_t)b * Ln + tn) * H4n + row];
        }
        const f4* hh = (const f4*)(h_s + half * 64);
        float a0 = 0.f, a1 = 0.f, a2 = 0.f, a3 = 0.f;
#pragma unroll
        for (int i = 0; i < 16; i += 4) {
            a0 = fma4v(w[i], hh[i], a0);
            a1 = fma4v(w[i + 1], hh[i + 1], a1);
            a2 = fma4v(w[i + 2], hh[i + 2], a2);
            a3 = fma4v(w[i + 3], hh[i + 3], a3);
        }
        float acc = (a0 + a1) + (a2 + a3);
        acc += __shfl_xor(acc, 1);
        if (half == 0) g_s[row] = acc + xw_v;
        __syncthreads();
        if (tid < Hn) {
            float ig = sigf(g_s[tid]);
            float fg = sigf(g_s[Hn + tid]);
            float gg = tanhf(g_s[2 * Hn + tid]);
            float og = sigf(g_s[3 * Hn + tid]);
            c_reg = fg * c_reg + ig * gg;
            float hv = og * tanhf(c_reg);
            h_s[tid] = hv;
            ho[((size_t)b * Ln + t) * (2 * Hn) + tid] = hv;
        }
        __syncthreads();
        xw_v = xw_n;
    }
}

// -------- codebook squared norms --------
__global__ void k_codenorm(const float* __restrict__ emb, float* __restrict__ c2) {
    int k = blockIdx.x * blockDim.x + threadIdx.x;
    if (k >= Kn) return;
    const f4* e4 = (const f4*)(emb + (size_t)k * Hn);
    float acc = 0.f;
    for (int i = 0; i < Hn / 4; ++i) {
        f4 v = e4[i];
        acc = fmaf(v.x, v.x, acc); acc = fmaf(v.y, v.y, acc);
        acc = fmaf(v.z, v.z, acc); acc = fmaf(v.w, v.w, acc);
    }
    c2[k] = acc;
}

// -------- VQ pick: argmin over dist row (first-index ties) + gather ---------
__global__ __launch_bounds__(128)
void k_vqpick(const float* __restrict__ dist, const float* __restrict__ emb,
              float* __restrict__ zq) {
    const int p = blockIdx.x, tid = threadIdx.x;
    __shared__ int best_s;
    if (tid < 64) {
        float best = 3.0e38f; int bi = 0;
        for (int j = 0; j < 8; ++j) {
            int k = j * 64 + tid;
            float d = dist[(size_t)p * Kn + k];
            if (d < best) { best = d; bi = k; }
        }
        for (int off = 32; off > 0; off >>= 1) {
            float ov = __shfl_xor(best, off);
            int   oi = __shfl_xor(bi, off);
            if (ov < best || (ov == best && oi < bi)) { best = ov; bi = oi; }
        }
        if (tid == 0) best_s = bi;
    }
    __syncthreads();
    zq[(size_t)p * Hn + tid] = emb[(size_t)best_s * Hn + tid];
}

// -------- decoder: 2 blocks/batch x 512 thr, quadrant split, 1 exchange -----
// side s owns gate rows {q*128 + s*64 + jj}: cell is local for h[s*64..s*64+64),
// only 64 h floats exchanged per step. Pinned/thread: whh 16f4 + wih 16f4 +
// w1 4f4 + vwr 32 + bdr = 177 VGPR.  __launch_bounds__(512,1): 1 block/CU ->
// 2 waves/EU -> 256-VGPR cap (R4/R6 evidence: 2nd arg is min BLOCKS/CU).
__global__ __launch_bounds__(512, 1)
void k_decoder(const float* __restrict__ kq_g, const float* __restrict__ vw_g,
               const float* __restrict__ cst_g,
               const float* __restrict__ W1R,  const float* __restrict__ b1_g,
               const float* __restrict__ WihR, const float* __restrict__ WhhR,
               const float* __restrict__ bd_g,
               float* gx, int* flags,
               float* __restrict__ dec_out, float* __restrict__ attn_w) {
    const int b    = blockIdx.x & 15;
    const int side = blockIdx.x >> 4;
    const int tid  = threadIdx.x;

    __shared__ __align__(16) f4 kq_lds[Ln * 32];       // 128 KB swizzled
    __shared__ __align__(16) float tok_s[D0n];
    __shared__ __align__(16) float x_s[Hn];
    __shared__ __align__(16) float h_s[Hn];
    __shared__ __align__(16) float g_loc[256];
    __shared__ float s_s[Ln];
    __shared__ float attn_sp[8][33];
    __shared__ float cst_s[Ln];
    __shared__ __align__(16) float b1_s[Hn];

    // ---- pinned weights ----
    const f4* WhhR4 = (const f4*)WhhR;
    const f4* WihR4 = (const f4*)WihR;
    const f4* W1R4  = (const f4*)W1R;
    f4 whh[16], wih[16], w1r[4];
#pragma unroll
    for (int f = 0; f < 16; ++f) whh[f] = WhhR4[f * 1024 + side * 512 + tid];
#pragma unroll
    for (int f = 0; f < 16; ++f) wih[f] = WihR4[f * 1024 + side * 512 + tid];
#pragma unroll
    for (int f = 0; f < 4; ++f)  w1r[f] = W1R4[f * 512 + tid];
    const int grow = (tid >> 7) * 128 + side * 64 + ((tid >> 1) & 63);
    float bdr = bd_g[grow];
    const int o = tid >> 3, slab = tid & 7;            // out phase map
    float vwr[32];
#pragma unroll
    for (int l = 0; l < 32; ++l)
        vwr[l] = vw_g[((size_t)b * Ln + slab * 32 + l) * D0n + o];
#pragma unroll
    for (int f = 0; f < 16; ++f) asm volatile("" : "+v"(whh[f]));
#pragma unroll
    for (int f = 0; f < 16; ++f) asm volatile("" : "+v"(wih[f]));
#pragma unroll
    for (int f = 0; f < 4; ++f)  asm volatile("" : "+v"(w1r[f]));
#pragma unroll
    for (int l = 0; l < 32; ++l) asm volatile("" : "+v"(vwr[l]));
    asm volatile("" : "+v"(bdr));

    // ---- stage KQ into LDS with XOR swizzle (phys f4 = f ^ (l&7)) ----
    const f4* kq4 = (const f4*)(kq_g + (size_t)b * Ln * Hn);
#pragma unroll
    for (int it = 0; it < 16; ++it) {
        int idx = it * 512 + tid;
        int l = idx >> 5, f = idx & 31;
        kq_lds[l * 32 + (f ^ (l & 7))] = kq4[idx];
    }
    if (tid < D0n) tok_s[tid] = 0.f;
    if (tid < Hn)  { h_s[tid] = 0.f; b1_s[tid] = b1_g[tid]; }
    if (tid < Ln)  cst_s[tid] = cst_g[(size_t)b * Ln + tid];
    float c_reg = 0.f;
    __syncthreads();

    float* gx_mine = gx + (b * 2 + side) * 128;
    float* gx_peer = gx + (b * 2 + (side ^ 1)) * 128;
    int* flag_mine = flags + (b * 2 + side);
    int* flag_peer = flags + (b * 2 + (side ^ 1));

    const int arow = tid >> 2, apart = tid & 3;        // x phase map
    const int el = tid >> 1, ep = tid & 1;             // score phase map
    const int gq = tid >> 7, gjj = (tid >> 1) & 63, ghalf = tid & 1;

    for (int t = 0; t < Ln; ++t) {
        // ---- A: x = relu(W1 @ tok + b1); 128 rows x 4 parts ----
        {
            const f4* t4 = (const f4*)tok_s;
            float u0 = fma4v(w1r[0], t4[apart * 4],     0.f);
            float u1 = fma4v(w1r[1], t4[apart * 4 + 1], 0.f);
            u0 = fma4v(w1r[2], t4[apart * 4 + 2], u0);
            u1 = fma4v(w1r[3], t4[apart * 4 + 3], u1);
            float a = u0 + u1;
            a += __shfl_xor(a, 1);
            a += __shfl_xor(a, 2);
            if (apart == 0) x_s[arow] = fmaxf(a + b1_s[arow], 0.f);
        }
        __syncthreads();
        // ---- gates (own 256 rows, 2 thr/row): all weights in VGPRs ----
        {
            const f4* x4 = (const f4*)(x_s + ghalf * 64);
            const f4* h4 = (const f4*)(h_s + ghalf * 64);
            float a0 = 0.f, a1 = 0.f, a2 = 0.f, a3 = 0.f;
#pragma unroll
            for (int f = 0; f < 16; f += 4) {
                a0 = fma4v(wih[f],     x4[f],     a0);
                a1 = fma4v(wih[f + 1], x4[f + 1], a1);
                a2 = fma4v(wih[f + 2], x4[f + 2], a2);
                a3 = fma4v(wih[f + 3], x4[f + 3], a3);
            }
#pragma unroll
            for (int f = 0; f < 16; f += 4) {
                a0 = fma4v(whh[f],     h4[f],     a0);
                a1 = fma4v(whh[f + 1], h4[f + 1], a1);
                a2 = fma4v(whh[f + 2], h4[f + 2], a2);
                a3 = fma4v(whh[f + 3], h4[f + 3], a3);
            }
            float a = (a0 + a1) + (a2 + a3);
            a += __shfl_xor(a, 1);
            if (ghalf == 0) g_loc[gq * 64 + gjj] = a + bdr;
        }
        __syncthreads();
        // ---- cell for own 64 components; h -> LDS + peer buffer ----
        if (tid < 64) {
            float ig = sigf(g_loc[tid]);
            float fg = sigf(g_loc[64 + tid]);
            float gg = tanhf(g_loc[128 + tid]);
            float og = sigf(g_loc[192 + tid]);
            c_reg = fg * c_reg + ig * gg;
            float hv = og * tanhf(c_reg);
            h_s[side * 64 + tid] = hv;
            __hip_atomic_store(&gx_mine[(t & 1) * 64 + tid], hv,
                               __ATOMIC_RELAXED, __HIP_MEMORY_SCOPE_AGENT);
        }
        __syncthreads();   // drains vmcnt: h stores complete
        if (tid == 0) {
            __hip_atomic_store(flag_mine, t + 1, __ATOMIC_RELEASE, __HIP_MEMORY_SCOPE_AGENT);
            while (__hip_atomic_load(flag_peer, __ATOMIC_ACQUIRE, __HIP_MEMORY_SCOPE_AGENT) < t + 1) {}
        }
        __syncthreads();
        if (tid < 64)
            h_s[(side ^ 1) * 64 + tid] =
                __hip_atomic_load(&gx_peer[(t & 1) * 64 + tid],
                                  __ATOMIC_RELAXED, __HIP_MEMORY_SCOPE_AGENT);
        __syncthreads();
        // ---- scores: s[l] = h . KQ[l] + cst[l]; 256 l x 2 parts ----
        {
            const f4* h4 = (const f4*)h_s;
            float e0 = 0.f, e1 = 0.f, e2 = 0.f, e3 = 0.f;
#pragma unroll
            for (int i = 0; i < 16; i += 4) {
                int f = ep * 16 + i;
                e0 = fma4v(kq_lds[el * 32 + ((f)     ^ (el & 7))], h4[f],     e0);
                e1 = fma4v(kq_lds[el * 32 + ((f + 1) ^ (el & 7))], h4[f + 1], e1);
                e2 = fma4v(kq_lds[el * 32 + ((f + 2) ^ (el & 7))], h4[f + 2], e2);
                e3 = fma4v(kq_lds[el * 32 + ((f + 3) ^ (el & 7))], h4[f + 3], e3);
            }
            float a = (e0 + e1) + (e2 + e3);
            a += __shfl_xor(a, 1);
            if (ep == 0) s_s[el] = a + cst_s[el];
        }
        __syncthreads();
        // ---- softmax, wave 0 only; side 0 writes attn_w ----
        if (tid < 64) {
            float v0 = s_s[tid],       v1 = s_s[tid + 64];
            float v2 = s_s[tid + 128], v3 = s_s[tid + 192];
            float m = fmaxf(fmaxf(v0, v1), fmaxf(v2, v3));
#pragma unroll
            for (int o2 = 32; o2 > 0; o2 >>= 1) m = fmaxf(m, __shfl_xor(m, o2));
            float e0 = expf(v0 - m), e1 = expf(v1 - m);
            float e2 = expf(v2 - m), e3 = expf(v3 - m);
            float s = (e0 + e1) + (e2 + e3);
#pragma unroll
            for (int o2 = 32; o2 > 0; o2 >>= 1) s += __shfl_xor(s, o2);
            float inv = 1.f / s;
            e0 *= inv; e1 *= inv; e2 *= inv; e3 *= inv;
            attn_sp[0][tid >> 5 ? tid & 31 : tid] = 0.f; // (dead store avoided below)
            attn_sp[(tid) >> 5][(tid) & 31] = e0;
            attn_sp[(tid + 64) >> 5][(tid) & 31] = e1;
            attn_sp[(tid + 128) >> 5][(tid) & 31] = e2;
            attn_sp[(tid + 192) >> 5][(tid) & 31] = e3;
            if (side == 0) {
                float* aw = attn_w + ((size_t)b * Ln + t) * Ln;
                aw[tid] = e0; aw[tid + 64] = e1;
                aw[tid + 128] = e2; aw[tid + 192] = e3;
            }
        }
        __syncthreads();
        // ---- out[o] = sum_l attn[l]*VW'[l][o]; 64 o x 8 slabs ----
        {
            const float* as = attn_sp[slab];
            float g0 = 0.f, g1 = 0.f, g2 = 0.f, g3 = 0.f;
#pragma unroll
            for (int l = 0; l < 32; l += 4) {
                g0 = fmaf(as[l],     vwr[l],     g0);
                g1 = fmaf(as[l + 1], vwr[l + 1], g1);
                g2 = fmaf(as[l + 2], vwr[l + 2], g2);
                g3 = fmaf(as[l + 3], vwr[l + 3], g3);
            }
            float a = (g0 + g1) + (g2 + g3);
            a += __shfl_xor(a, 1);
            a += __shfl_xor(a, 2);
            a += __shfl_xor(a, 4);
            if (slab == 0) {
                tok_s[o] = a;
                if (side == 1) dec_out[((size_t)b * Ln + t) * D0n + o] = a;
            }
        }
        __syncthreads();
    }
}

extern "C" void kernel_launch(void* const* d_in, const int* in_sizes, int n_in,
                              void* d_out, int out_size, void* d_ws, size_t ws_size,
                              hipStream_t stream) {
    const float* inputs     = (const float*)d_in[0];
    const float* in_mask    = (const float*)d_in[2];
    const float* enc_lin1_W = (const float*)d_in[3];
    const float* enc_lin1_b = (const float*)d_in[4];
    const float* enc_Wih_f  = (const float*)d_in[5];
    const float* enc_Whh_f  = (const float*)d_in[6];
    const float* enc_b_f    = (const float*)d_in[7];
    const float* enc_Wih_b  = (const float*)d_in[8];
    const float* enc_Whh_b  = (const float*)d_in[9];
    const float* enc_b_b    = (const float*)d_in[10];
    const float* enc_lin2_W = (const float*)d_in[11];
    const float* enc_lin2_b = (const float*)d_in[12];
    const float* vq_emb     = (const float*)d_in[13];
    const float* dec_lin1_W = (const float*)d_in[14];
    const float* dec_lin1_b = (const float*)d_in[15];
    const float* dec_Wih    = (const float*)d_in[16];
    const float* dec_Whh    = (const float*)d_in[17];
    const float* dec_b      = (const float*)d_in[18];
    const float* attn_Wq    = (const float*)d_in[19];
    const float* attn_bq    = (const float*)d_in[20];
    const float* attn_Wk    = (const float*)d_in[21];
    const float* attn_bk    = (const float*)d_in[22];
    const float* attn_Wv    = (const float*)d_in[23];
    const float* attn_bv    = (const float*)d_in[24];
    const float* dec_lin2_W = (const float*)d_in[25];
    const float* dec_lin2_b = (const float*)d_in[26];

    float* out     = (float*)d_out;
    float* dec_out = out;                       // 16*256*64   = 262144
    float* attn_w  = out + 262144;              // 16*256*256  = 1048576
    float* ze      = out + 1310720;             // 16*256*128  = 524288
    float* zq      = out + 1835008;             // 16*256*128  = 524288

    float* ws    = (float*)d_ws;
    float* enc_x = ws;                          // 524288
    float* xWf   = enc_x + 524288;              // 2097152
    float* xWb   = xWf + 2097152;               // 2097152
    float* hcat  = xWb + 2097152;               // 1048576 (hf|hb interleaved rows)
    float* kp    = hcat + 1048576;              // 524288
    float* vp    = kp + 524288;                 // 524288
    float* c2    = vp + 524288;                 // 512
    float* gxbuf = c2 + 512;                    // 16*2*128 = 4096
    int*   flags = (int*)(gxbuf + 4096);        // 32 ints
    // aliases into dead regions:
    float* WqT   = enc_x;                       // enc_x dead after xWf/xWb
    float* WhhR  = enc_x + 16384;               // 65536
    float* WihR  = enc_x + 16384 + 65536;       // 65536
    float* W1R   = enc_x + 16384 + 2 * 65536;   // 8192
    float* dist  = xWf;                         // 4096*512 = 2097152 (dead post-LSTM)
    float* kq    = xWb;                         // 524288  (dead post-LSTM)
    float* vw    = xWb + 524288;                // 262144
    float* cst   = xWb + 786432;                // 4096

    dim3 blk(256);
    // ---- encoder front ----
    k_gemm<<<dim3(2, 64), blk, 0, stream>>>(inputs, enc_lin1_W, enc_lin1_b, enc_x, D0n, Hn, 1, 1.f);
    k_gemm<<<dim3(8, 64), blk, 0, stream>>>(enc_x, enc_Wih_f, enc_b_f, xWf, Hn, H4n, 0, 1.f);
    k_gemm<<<dim3(8, 64), blk, 0, stream>>>(enc_x, enc_Wih_b, enc_b_b, xWb, Hn, H4n, 0, 1.f);
    // ---- weight rearrangements into enc_x region (dead now) ----
    k_transpose<<<64, 256, 0, stream>>>(attn_Wq, WqT, Hn, Hn);
    k_rearrG3<<<64, 256, 0, stream>>>((const f4*)dec_Whh, (f4*)WhhR);
    k_rearrG3<<<64, 256, 0, stream>>>((const f4*)dec_Wih, (f4*)WihR);
    k_rearrW14<<<8, 256, 0, stream>>>((const f4*)dec_lin1_W, (f4*)W1R);
    k_zero<<<1, 64, 0, stream>>>(flags, 32);
    // ---- BiLSTM ----
    k_lstm_scan<<<32, 1024, 0, stream>>>(xWf, xWb, enc_Whh_f, enc_Whh_b, hcat);
    k_gemm<<<dim3(2, 64), blk, 0, stream>>>(hcat, enc_lin2_W, enc_lin2_b, ze, 2 * Hn, Hn, 0, 1.f);
    // ---- VQ: dist GEMM + argmin/gather ----
    k_codenorm<<<2, 256, 0, stream>>>(vq_emb, c2);
    k_gemm<<<dim3(8, 64), blk, 0, stream>>>(ze, vq_emb, c2, dist, Hn, Kn, 0, -2.f);
    k_vqpick<<<BLn, 128, 0, stream>>>(dist, vq_emb, zq);
    // ---- attention precomputes (dec_in == zq) ----
    k_gemm<<<dim3(2, 64), blk, 0, stream>>>(zq, attn_Wk, attn_bk, kp, Hn, Hn, 0, 1.f);
    k_gemm<<<dim3(2, 64), blk, 0, stream>>>(zq, attn_Wv, attn_bv, vp, Hn, Hn, 0, 1.f);
    k_gemm<<<dim3(2, 64), blk, 0, stream>>>(kp, WqT, nullptr, kq, Hn, Hn, 0, 0.088388347648318447f);
    k_gemm<<<dim3(1, 64), blk, 0, stream>>>(vp, dec_lin2_W, dec_lin2_b, vw, Hn, D0n, 0, 1.f);
    k_cst<<<Bn, 256, 0, stream>>>(kp, attn_bq, in_mask, cst);
    // ---- decoder: 32 blocks = 16 batches x 2 sides, 512 thr ----
    k_decoder<<<32, 512, 0, stream>>>(kq, vw, cst,
                                      W1R, dec_lin1_b,
                                      WihR, WhhR, dec_b,
                                      gxbuf, flags,
                                      dec_out, attn_w);
}